// Round 5
// baseline (583.689 us; speedup 1.0000x reference)
//
#include <hip/hip_runtime.h>
#include <math.h>
#include <stdint.h>

// LinearAttention  N=4, S=8192, D_IN=1024, ATTN_DIM=1024, OUT_DIM=1024
// R5: out_mfma widened to BM=128 x BN=128 (1.0 KB staged / MFMA, was 1.5);
// 4x wtrans merged into one launch. qkv_mfma unchanged (at m97-structure
// plateau: 818 TF, MfmaUtil 35.5 / VALUBusy 44 == m98 profile).
// LDS layout everywhere: XOR-swizzled chunks, slot = r*8 + (j^(r&7)),
// staged via global_load_lds width=16 (swizzle applied to the GLOBAL per-lane
// address; LDS dest stays wave-uniform base + lane*16).

#define S_LEN 8192
#define M_TOT 32768

typedef __attribute__((ext_vector_type(8))) __bf16 bf16x8;
typedef __attribute__((ext_vector_type(8))) unsigned short ushort8;
typedef __attribute__((ext_vector_type(4))) float f32x4;

__device__ __forceinline__ unsigned short f2bf(float f) {
    unsigned int u = __builtin_bit_cast(unsigned int, f);
    unsigned int r = (u + 0x7fffu + ((u >> 16) & 1u)) >> 16;   // RNE
    return (unsigned short)r;
}
__device__ __forceinline__ float bf2f(unsigned short s) {
    unsigned int u = ((unsigned int)s) << 16;
    return __builtin_bit_cast(float, u);
}
__device__ __forceinline__ float elu1(float v) { return v > 0.f ? v + 1.f : __expf(v); }
__device__ __forceinline__ float gelu_tanh(float v) {
    float u = 1.5957691216057308f * (v + 0.044715f * v * v * v);
    float e = __expf(u);
    float th = 1.f - 2.f / (e + 1.f);
    return 0.5f * v * (1.f + th);
}

// async global->LDS, 16B per lane; LDS dest = wave-uniform base + lane*16
__device__ __forceinline__ void glds16(const void* g, void* l) {
    __builtin_amdgcn_global_load_lds(
        (const __attribute__((address_space(1))) unsigned int*)(uintptr_t)g,
        (__attribute__((address_space(3))) unsigned int*)(uintptr_t)l, 16, 0, 0);
}

// ---------------------------------------------------------------------------
// x fp32 -> bf16 (row-major, unchanged layout), one half (16384 rows) per call
// ---------------------------------------------------------------------------
__global__ __launch_bounds__(256) void xconv(const float* __restrict__ x,
                                             unsigned short* __restrict__ xb)
{
    const size_t base = ((size_t)blockIdx.x * 256 + threadIdx.x) * 8;
    float4 a = *(const float4*)&x[base];
    float4 b = *(const float4*)&x[base + 4];
    ushort8 o;
    o[0] = f2bf(a.x); o[1] = f2bf(a.y); o[2] = f2bf(a.z); o[3] = f2bf(a.w);
    o[4] = f2bf(b.x); o[5] = f2bf(b.y); o[6] = f2bf(b.z); o[7] = f2bf(b.w);
    *(ushort8*)&xb[base] = o;
}

// ---------------------------------------------------------------------------
// weight transpose + convert: w[k][n] fp32 (1024x1024) -> wT[n][k] bf16
// all 4 weights in one launch (blockIdx.z selects matrix)
// ---------------------------------------------------------------------------
__global__ __launch_bounds__(256) void wtrans4(
    const float* __restrict__ w0, const float* __restrict__ w1,
    const float* __restrict__ w2, const float* __restrict__ w3,
    unsigned short* __restrict__ wT0, unsigned short* __restrict__ wT1,
    unsigned short* __restrict__ wT2, unsigned short* __restrict__ wT3)
{
    const int z = blockIdx.z;
    const float* w = (z == 0) ? w0 : (z == 1) ? w1 : (z == 2) ? w2 : w3;
    unsigned short* wT = (z == 0) ? wT0 : (z == 1) ? wT1 : (z == 2) ? wT2 : wT3;

    __shared__ float tile[64][65];
    const int t  = threadIdx.x;
    const int n0 = blockIdx.x * 64;
    const int k0 = blockIdx.y * 64;
    const int r  = t >> 2;
    const int c4 = (t & 3) * 16;
    #pragma unroll
    for (int j = 0; j < 4; ++j) {
        float4 v = *(const float4*)&w[(size_t)(k0 + r) * 1024 + n0 + c4 + j * 4];
        tile[r][c4 + j * 4 + 0] = v.x; tile[r][c4 + j * 4 + 1] = v.y;
        tile[r][c4 + j * 4 + 2] = v.z; tile[r][c4 + j * 4 + 3] = v.w;
    }
    __syncthreads();
    const int nn = t >> 2;
    const int kc = (t & 3) * 16;
    ushort8 o0, o1;
    #pragma unroll
    for (int j = 0; j < 8; ++j) o0[j] = f2bf(tile[kc + j][nn]);
    #pragma unroll
    for (int j = 0; j < 8; ++j) o1[j] = f2bf(tile[kc + 8 + j][nn]);
    *(ushort8*)&wT[(size_t)(n0 + nn) * 1024 + k0 + kc]     = o0;
    *(ushort8*)&wT[(size_t)(n0 + nn) * 1024 + k0 + kc + 8] = o1;
}

// ---------------------------------------------------------------------------
// Phase A: fused QKV.  BM=128, BN=64 (per matrix), BK=64, 4 waves (2x2),
// wave tile 64x32 per matrix = 4x2 tiles of 16x16, MFMA 16x16x32 bf16.
// ---------------------------------------------------------------------------
__global__ __launch_bounds__(256) void qkv_mfma(
    const unsigned short* __restrict__ xb,       // half: [16384,1024] bf16
    const unsigned short* __restrict__ wqT,
    const unsigned short* __restrict__ wkT,
    const unsigned short* __restrict__ wvT,
    const float* __restrict__ bq, const float* __restrict__ bk,
    const float* __restrict__ bv,
    unsigned short* __restrict__ Qout,           // full [32768,1024]
    float* __restrict__ KV, float* __restrict__ Ks,
    int moff)
{
    __shared__ unsigned short Alds[128 * 64];
    __shared__ unsigned short Blds[3][64 * 64];
    __shared__ float redkv[8][64];
    __shared__ float redks[8][64];

    const int t  = threadIdx.x;
    const int h0 = blockIdx.x * 64;
    const int m0 = blockIdx.y * 128;             // local row base within half
    const int mg = moff + m0;                    // global row base
    const int n  = mg >> 13;

    const int lane = t & 63, wid = t >> 6;
    const int wm = wid >> 1, wn = wid & 1;
    const int lr = lane & 15, quad = lane >> 4;

    f32x4 accq[4][2], acck[4][2], accv[4][2];
    #pragma unroll
    for (int mi = 0; mi < 4; ++mi)
        #pragma unroll
        for (int nj = 0; nj < 2; ++nj) {
            accq[mi][nj] = (f32x4){0.f, 0.f, 0.f, 0.f};
            acck[mi][nj] = (f32x4){0.f, 0.f, 0.f, 0.f};
            accv[mi][nj] = (f32x4){0.f, 0.f, 0.f, 0.f};
        }

    for (int k0 = 0; k0 < 1024; k0 += 64) {
        __syncthreads();
        #pragma unroll
        for (int i = 0; i < 4; ++i) {
            const int s = wid * 256 + i * 64 + lane;
            const int r = s >> 3;
            const int j = (s & 7) ^ (r & 7);
            glds16(&xb[(size_t)(m0 + r) * 1024 + k0 + j * 8],
                   &Alds[(wid * 256 + i * 64) * 8]);
        }
        #pragma unroll
        for (int i = 0; i < 2; ++i) {
            const int s = wid * 128 + i * 64 + lane;
            const int r = s >> 3;
            const int j = (s & 7) ^ (r & 7);
            const size_t go = (size_t)(h0 + r) * 1024 + k0 + j * 8;
            const int lo = (wid * 128 + i * 64) * 8;
            glds16(&wqT[go], &Blds[0][lo]);
            glds16(&wkT[go], &Blds[1][lo]);
            glds16(&wvT[go], &Blds[2][lo]);
        }
        __syncthreads();
        #pragma unroll
        for (int ks = 0; ks < 2; ++ks) {
            bf16x8 af[4];
            #pragma unroll
            for (int mi = 0; mi < 4; ++mi) {
                const int r = wm * 64 + mi * 16 + lr;
                const int off = r * 64 + (((ks * 4 + quad) ^ (r & 7)) * 8);
                af[mi] = __builtin_bit_cast(bf16x8, *(const ushort8*)&Alds[off]);
            }
            bf16x8 bfq[2], bfk[2], bfv[2];
            #pragma unroll
            for (int nj = 0; nj < 2; ++nj) {
                const int r = wn * 32 + nj * 16 + lr;
                const int off = r * 64 + (((ks * 4 + quad) ^ (r & 7)) * 8);
                bfq[nj] = __builtin_bit_cast(bf16x8, *(const ushort8*)&Blds[0][off]);
                bfk[nj] = __builtin_bit_cast(bf16x8, *(const ushort8*)&Blds[1][off]);
                bfv[nj] = __builtin_bit_cast(bf16x8, *(const ushort8*)&Blds[2][off]);
            }
            #pragma unroll
            for (int mi = 0; mi < 4; ++mi)
                #pragma unroll
                for (int nj = 0; nj < 2; ++nj) {
                    accq[mi][nj] = __builtin_amdgcn_mfma_f32_16x16x32_bf16(af[mi], bfq[nj], accq[mi][nj], 0, 0, 0);
                    acck[mi][nj] = __builtin_amdgcn_mfma_f32_16x16x32_bf16(af[mi], bfk[nj], acck[mi][nj], 0, 0, 0);
                    accv[mi][nj] = __builtin_amdgcn_mfma_f32_16x16x32_bf16(af[mi], bfv[nj], accv[mi][nj], 0, 0, 0);
                }
        }
    }

    float bqv[2], bkv[2], bvv[2];
    #pragma unroll
    for (int nj = 0; nj < 2; ++nj) {
        const int h = h0 + wn * 32 + nj * 16 + lr;
        bqv[nj] = bq[h]; bkv[nj] = bk[h]; bvv[nj] = bv[h];
    }
    float kvp[2] = {0.f, 0.f}, ksp[2] = {0.f, 0.f};
    #pragma unroll
    for (int mi = 0; mi < 4; ++mi)
        #pragma unroll
        for (int nj = 0; nj < 2; ++nj) {
            const int h = h0 + wn * 32 + nj * 16 + lr;
            #pragma unroll
            for (int r = 0; r < 4; ++r) {
                const int m = mg + wm * 64 + mi * 16 + quad * 4 + r;
                float q = elu1(accq[mi][nj][r] + bqv[nj]);
                Qout[(size_t)m * 1024 + h] = f2bf(q);
                float kk = elu1(acck[mi][nj][r] + bkv[nj]);
                float vv = accv[mi][nj][r] + bvv[nj];
                kvp[nj] = fmaf(kk, vv, kvp[nj]);
                ksp[nj] += kk;
            }
        }
    #pragma unroll
    for (int nj = 0; nj < 2; ++nj) {
        redkv[wm * 4 + quad][wn * 32 + nj * 16 + lr] = kvp[nj];
        redks[wm * 4 + quad][wn * 32 + nj * 16 + lr] = ksp[nj];
    }
    __syncthreads();
    if (t < 64) {
        float s = 0.f;
        #pragma unroll
        for (int g = 0; g < 8; ++g) s += redkv[g][t];
        atomicAdd(&KV[n * 1024 + h0 + t], s);
    } else if (t < 128) {
        const int c = t - 64;
        float s = 0.f;
        #pragma unroll
        for (int g = 0; g < 8; ++g) s += redks[g][c];
        atomicAdd(&Ks[n * 1024 + h0 + c], s);
    }
}

// ---------------------------------------------------------------------------
// V' = Q*KV / (Q*Ksum + 1e-6), elementwise in-place on Q (bf16)
// ---------------------------------------------------------------------------
__global__ __launch_bounds__(256) void vprime(
    unsigned short* __restrict__ Q,
    const float* __restrict__ KV, const float* __restrict__ Ks)
{
    const size_t idx  = (size_t)blockIdx.x * 256 + threadIdx.x;
    const size_t base = idx * 8;
    const int h = (int)(base & 1023);
    const int n = (int)(base >> 23);
    ushort8 q8 = *(ushort8*)&Q[base];
    const float* kvp = &KV[n * 1024 + h];
    const float* ksp = &Ks[n * 1024 + h];
    ushort8 o;
    #pragma unroll
    for (int j = 0; j < 8; ++j) {
        float qf = bf2f(q8[j]);
        float vp = qf * kvp[j] * __builtin_amdgcn_rcpf(fmaf(qf, ksp[j], 1e-6f));
        o[j] = f2bf(vp);
    }
    *(ushort8*)&Q[base] = o;
}

// ---------------------------------------------------------------------------
// Phase B: out = gelu(V' @ wo + bo).  BM=128, BN=128, BK=64, 4 waves (2x2),
// wave tile 64x64 = 4x4 tiles of 16x16.  glds + swizzle staging.
// ---------------------------------------------------------------------------
__global__ __launch_bounds__(256) void out_mfma(
    const unsigned short* __restrict__ Vp,
    const unsigned short* __restrict__ woT,
    const float* __restrict__ bo, float* __restrict__ out)
{
    __shared__ unsigned short Alds[128 * 64];
    __shared__ unsigned short Blds[128 * 64];

    const int t  = threadIdx.x;
    const int h0 = blockIdx.x * 128;
    const int m0 = blockIdx.y * 128;

    const int lane = t & 63, wid = t >> 6;
    const int wm = wid >> 1, wn = wid & 1;
    const int lr = lane & 15, quad = lane >> 4;

    f32x4 acc[4][4];
    #pragma unroll
    for (int mi = 0; mi < 4; ++mi)
        #pragma unroll
        for (int nj = 0; nj < 4; ++nj) acc[mi][nj] = (f32x4){0.f, 0.f, 0.f, 0.f};

    for (int k0 = 0; k0 < 1024; k0 += 64) {
        __syncthreads();
        #pragma unroll
        for (int i = 0; i < 4; ++i) {
            const int s = wid * 256 + i * 64 + lane;
            const int r = s >> 3;
            const int j = (s & 7) ^ (r & 7);
            glds16(&Vp[(size_t)(m0 + r) * 1024 + k0 + j * 8],
                   &Alds[(wid * 256 + i * 64) * 8]);
            glds16(&woT[(size_t)(h0 + r) * 1024 + k0 + j * 8],
                   &Blds[(wid * 256 + i * 64) * 8]);
        }
        __syncthreads();
        #pragma unroll
        for (int ks = 0; ks < 2; ++ks) {
            bf16x8 af[4];
            #pragma unroll
            for (int mi = 0; mi < 4; ++mi) {
                const int r = wm * 64 + mi * 16 + lr;
                const int off = r * 64 + (((ks * 4 + quad) ^ (r & 7)) * 8);
                af[mi] = __builtin_bit_cast(bf16x8, *(const ushort8*)&Alds[off]);
            }
            bf16x8 bf_[4];
            #pragma unroll
            for (int nj = 0; nj < 4; ++nj) {
                const int r = wn * 64 + nj * 16 + lr;
                const int off = r * 64 + (((ks * 4 + quad) ^ (r & 7)) * 8);
                bf_[nj] = __builtin_bit_cast(bf16x8, *(const ushort8*)&Blds[off]);
            }
            #pragma unroll
            for (int mi = 0; mi < 4; ++mi)
                #pragma unroll
                for (int nj = 0; nj < 4; ++nj)
                    acc[mi][nj] = __builtin_amdgcn_mfma_f32_16x16x32_bf16(af[mi], bf_[nj], acc[mi][nj], 0, 0, 0);
        }
    }

    float bov[4];
    #pragma unroll
    for (int nj = 0; nj < 4; ++nj) bov[nj] = bo[h0 + wn * 64 + nj * 16 + lr];
    #pragma unroll
    for (int mi = 0; mi < 4; ++mi)
        #pragma unroll
        for (int nj = 0; nj < 4; ++nj) {
            const int h = h0 + wn * 64 + nj * 16 + lr;
            #pragma unroll
            for (int r = 0; r < 4; ++r) {
                const int m = m0 + wm * 64 + mi * 16 + quad * 4 + r;
                out[(size_t)m * 1024 + h] = gelu_tanh(acc[mi][nj][r] + bov[nj]);
            }
        }
}

extern "C" void kernel_launch(void* const* d_in, const int* in_sizes, int n_in,
                              void* d_out, int out_size, void* d_ws, size_t ws_size,
                              hipStream_t stream)
{
    const float* x  = (const float*)d_in[0];
    const float* wq = (const float*)d_in[1];
    const float* bq = (const float*)d_in[2];
    const float* wk = (const float*)d_in[3];
    const float* bk = (const float*)d_in[4];
    const float* wv = (const float*)d_in[5];
    const float* bv = (const float*)d_in[6];
    const float* wo = (const float*)d_in[7];
    const float* bo = (const float*)d_in[8];
    float* out = (float*)d_out;

    // ws layout (bytes):
    //   [0, 64M)        Q / V' bf16  (32768 x 1024)
    //   [64M, 96M)      xb bf16 half (16384 x 1024), reused for both halves
    //   [96M, 104M)     wqT, wkT, wvT, woT bf16 (2MB each)
    //   [104M, ...)     KV fp32 [4,1024], Ks fp32 [4,1024]
    char* wsb = (char*)d_ws;
    unsigned short* Qws = (unsigned short*)wsb;
    unsigned short* xb  = (unsigned short*)(wsb + 67108864ULL);
    unsigned short* wqT = (unsigned short*)(wsb + 100663296ULL);
    unsigned short* wkT = wqT + 1048576;
    unsigned short* wvT = wkT + 1048576;
    unsigned short* woT = wvT + 1048576;
    float* KV = (float*)(wsb + 100663296ULL + 4ULL * 2097152);
    float* Ks = KV + 4 * 1024;

    hipMemsetAsync(KV, 0, 2 * 4 * 1024 * sizeof(float), stream);

    wtrans4<<<dim3(16, 16, 4), 256, 0, stream>>>(wq, wk, wv, wo, wqT, wkT, wvT, woT);

    for (int half = 0; half < 2; ++half) {
        xconv<<<8192, 256, 0, stream>>>(x + (size_t)half * 16384 * 1024, xb);
        qkv_mfma<<<dim3(16, 128), 256, 0, stream>>>(xb, wqT, wkT, wvT, bq, bk, bv,
                                                    Qws, KV, Ks, half * 16384);
    }
    vprime<<<16384, 256, 0, stream>>>(Qws, KV, Ks);
    out_mfma<<<dim3(8, 256), 256, 0, stream>>>(Qws, woT, bo, out);
}